// Round 24
// baseline (744.805 us; speedup 1.0000x reference)
//
#include <hip/hip_runtime.h>
#include <hip/hip_bf16.h>
#include <hip/hip_fp16.h>

#define NHID 256   // HEADS*H
#define HDIM 64
#define HEADS 4
#define LAYERS 5
#define LOG2E 1.4426950408889634f

using half8 = __attribute__((ext_vector_type(8))) _Float16;
using h2    = __attribute__((ext_vector_type(2))) _Float16;
using f32x4 = __attribute__((ext_vector_type(4))) float;

#define BC(x) __builtin_bit_cast(h2, x)

// ---------------- CSR build (self-loops included: grid covers E+n) ----------------
__global__ void count_deg(const int* __restrict__ dst, int* __restrict__ counts, int E, int n) {
    int i = blockIdx.x * blockDim.x + threadIdx.x;
    if (i < E) atomicAdd(&counts[dst[i]], 1);
    else if (i < E + n) atomicAdd(&counts[i - E], 1);   // self loop
}

__global__ __launch_bounds__(256) void scan_partial(const int* __restrict__ counts,
                                                    int* __restrict__ out,
                                                    int* __restrict__ partials, int n) {
    __shared__ int buf[256];
    int tid = threadIdx.x;
    int i = blockIdx.x * 256 + tid;
    int v = (i < n) ? counts[i] : 0;
    buf[tid] = v;
    __syncthreads();
    for (int o = 1; o < 256; o <<= 1) {
        int t = (tid >= o) ? buf[tid - o] : 0;
        __syncthreads();
        buf[tid] += t;
        __syncthreads();
    }
    if (i < n) out[i] = buf[tid] - v;              // exclusive within chunk
    if (tid == 255) partials[blockIdx.x] = buf[255];
}

__global__ __launch_bounds__(256) void scan_partials_scan(int* __restrict__ partials,
                                                          int* __restrict__ out,
                                                          int nblk, int n) {
    __shared__ int buf[256];
    int tid = threadIdx.x;
    int v = (tid < nblk) ? partials[tid] : 0;
    buf[tid] = v;
    __syncthreads();
    for (int o = 1; o < 256; o <<= 1) {
        int t = (tid >= o) ? buf[tid - o] : 0;
        __syncthreads();
        buf[tid] += t;
        __syncthreads();
    }
    if (tid < nblk) partials[tid] = buf[tid] - v;  // exclusive chunk offsets
    if (tid == 255) out[n] = buf[255];
}

// phase 3: add chunk offset; writes BOTH row_ptr and row_fill (saves a copy pass)
__global__ __launch_bounds__(256) void scan_add_offsets2(int* __restrict__ out,
                                                         int* __restrict__ out2,
                                                         const int* __restrict__ partials, int n) {
    int i = blockIdx.x * 256 + threadIdx.x;
    if (i < n) {
        int v = out[i] + partials[blockIdx.x];
        out[i] = v;
        out2[i] = v;
    }
}

// scatter: col_src holds PRE-SHIFTED byte row offsets (src * 512)
__global__ void scatter_edges(const int* __restrict__ src, const int* __restrict__ dst,
                              int* __restrict__ row_fill, int* __restrict__ col_src, int E, int n) {
    int i = blockIdx.x * blockDim.x + threadIdx.x;
    if (i < E) {
        int p = atomicAdd(&row_fill[dst[i]], 1);
        col_src[p] = src[i] << 9;
    } else if (i < E + n) {
        int node = i - E;
        int p = atomicAdd(&row_fill[node], 1);
        col_src[p] = node << 9;                     // self loop
    }
}

// ---------------- W -> fp16 MFMA B-fragment layout ----------------
// Wfrag[layer][t(32)][kh(2)][lane(64)][8]: lane l, elem j: k = kh*32+(l>>4)*8+j,
// col = t*16+(l&15); col<256 -> Wl, else Wr. 32768 halves per layer.
__global__ __launch_bounds__(256) void wprep(const float* __restrict__ Wl,
                                             const float* __restrict__ Wr,
                                             __half* __restrict__ Wfrag) {
    int layer = blockIdx.x >> 4;
    int idx = (blockIdx.x & 15) * 256 + threadIdx.x;  // 0..4095
    int t = idx >> 7, kh = (idx >> 6) & 1, lane = idx & 63;
    const float* WlL = Wl + (size_t)layer * 64 * 256;
    const float* WrL = Wr + (size_t)layer * 64 * 256;
    int col = t * 16 + (lane & 15);
    __half* outp = Wfrag + (size_t)layer * 32768 + ((size_t)(t * 2 + kh) * 64 + lane) * 8;
#pragma unroll
    for (int j = 0; j < 8; ++j) {
        int k = kh * 32 + (lane >> 4) * 8 + j;
        float v = (col < 256) ? WlL[k * 256 + col] : WrL[k * 256 + (col - 256)];
        outp[j] = __float2half(v);
    }
}

// ---------------- convert node features to fp16 ----------------
__global__ void conv_h16(const float* __restrict__ h, __half* __restrict__ h16, int total) {
    int i = blockIdx.x * blockDim.x + threadIdx.x;
    if (i < total) h16[i] = __float2half(h[i]);
}

// ---------------- MFMA GEMM pair (R18 layout, reverted): A = h rows, B = Wfrag ----
__global__ __launch_bounds__(256) void gemm_mfma(const __half* __restrict__ h16,
                                                 const __half* __restrict__ Wfrag,
                                                 const float* __restrict__ bl,
                                                 const float* __restrict__ br,
                                                 __half* __restrict__ xlh,
                                                 __half* __restrict__ xrh, int n) {
    int w = threadIdx.x >> 6, l = threadIdx.x & 63;
    int row0 = blockIdx.x * 64 + w * 16;
    if (row0 >= n) return;
    int arow = row0 + (l & 15);
    half8 A0 = *(const half8*)(h16 + (size_t)arow * 64 + (l >> 4) * 8);        // k 0..31
    half8 A1 = *(const half8*)(h16 + (size_t)arow * 64 + 32 + (l >> 4) * 8);   // k 32..63
    int orow = row0 + (l >> 4) * 4;
#pragma unroll
    for (int t = 0; t < 32; ++t) {
        half8 B0 = *(const half8*)(Wfrag + ((size_t)(t * 2 + 0) * 64 + l) * 8);
        half8 B1 = *(const half8*)(Wfrag + ((size_t)(t * 2 + 1) * 64 + l) * 8);
        f32x4 acc = {0.f, 0.f, 0.f, 0.f};
        acc = __builtin_amdgcn_mfma_f32_16x16x32_f16(A0, B0, acc, 0, 0, 0);
        acc = __builtin_amdgcn_mfma_f32_16x16x32_f16(A1, B1, acc, 0, 0, 0);
        int col = t * 16 + (l & 15);
        if (col < 256) {
            float b = bl[col];
#pragma unroll
            for (int j = 0; j < 4; ++j)
                xlh[(size_t)(orow + j) * 256 + col] = __float2half(acc[j] + b);
        } else {
            float b = br[col - 256];
#pragma unroll
            for (int j = 0; j < 4; ++j)
                xrh[(size_t)(orow + j) * 256 + (col - 256)] = __float2half(acc[j] + b);
        }
    }
}

// ---------------- DPP helper ----------------
template <int CTRL>
__device__ __forceinline__ float dpp_mov_f32(float x) {
    return __int_as_float(__builtin_amdgcn_update_dpp(0, __float_as_int(x), CTRL, 0xf, 0xf, false));
}

// ---------------- fused GATv2: 1 wave/node, 4 EDGES per iteration ----------------
// lane l: edge slot e = l>>4, sub-lane j = l&15 owns halves [16j,16j+16) (32B).
// head = j>>2 (a quad) -> score reduce = 2 intra-quad DPP ops.
// Unmatched slots keep m=NEGBIG; annihilated in the 2-stage slot merge.
__global__ __launch_bounds__(256) void gat_node(const __half* __restrict__ xlh,
                                                const __half* __restrict__ xrh,
                                                const int* __restrict__ row_ptr,
                                                const int* __restrict__ col_src,
                                                const float* __restrict__ att,     // [4][64] this layer
                                                const float* __restrict__ gbias,   // [64] this layer
                                                const float* __restrict__ h_res,   // residual or null
                                                float* __restrict__ h_out,
                                                __half* __restrict__ h16_out, int n) {
    int wid  = threadIdx.x >> 6;
    int l    = threadIdx.x & 63;
    int node = blockIdx.x * 4 + wid;
    if (node >= n) return;
    int j = l & 15;                         // sub-lane: halves 16j..16j+15
    int e = l >> 4;                         // edge slot 0..3
    int laneoff = j << 5;                   // 32B per sub-lane within 512B row

    const char* xlb = (const char*)xlh;
    const char* xrb = (const char*)xrh + (size_t)node * 512 + laneoff;
    uint4 xq0 = *(const uint4*)xrb;
    uint4 xq1 = *(const uint4*)(xrb + 16);
    h2 xr[8];
    xr[0] = BC(xq0.x); xr[1] = BC(xq0.y); xr[2] = BC(xq0.z); xr[3] = BC(xq0.w);
    xr[4] = BC(xq1.x); xr[5] = BC(xq1.y); xr[6] = BC(xq1.z); xr[7] = BC(xq1.w);

    // att linear at 16j (identity: (j>>2)*64 + (j&3)*16 + k == 16j + k); fp16 + LOG2E
    const float* ap = att + j * 16;
    h2 av[8];
#pragma unroll
    for (int k = 0; k < 8; ++k) {
        av[k].x = (_Float16)(ap[2 * k]     * LOG2E);
        av[k].y = (_Float16)(ap[2 * k + 1] * LOG2E);
    }

    h2 c02 = {(_Float16)0.2f, (_Float16)0.2f};
    const float NEGBIG = -1.0e30f;
    float m = NEGBIG, s = 0.f;
    float ac[16];
#pragma unroll
    for (int k = 0; k < 16; ++k) ac[k] = 0.f;

    int e0 = row_ptr[node], e1 = row_ptr[node + 1];   // deg >= 1 (self loop)
    int off0 = col_src[e0 + e];                        // padded reads past e1 are safe
    uint4 xa0 = *(const uint4*)(xlb + (size_t)(unsigned)off0 + laneoff);
    uint4 xa1 = *(const uint4*)(xlb + (size_t)(unsigned)off0 + laneoff + 16);
    int off1 = col_src[e0 + 4 + e];
    uint4 xb0 = *(const uint4*)(xlb + (size_t)(unsigned)off1 + laneoff);
    uint4 xb1 = *(const uint4*)(xlb + (size_t)(unsigned)off1 + laneoff + 16);

    for (int base = e0; base < e1; base += 4) {
        uint4 r0 = xa0, r1 = xa1;
        xa0 = xb0; xa1 = xb1;
        int off2 = col_src[base + 8 + e];
        xb0 = *(const uint4*)(xlb + (size_t)(unsigned)off2 + laneoff);
        xb1 = *(const uint4*)(xlb + (size_t)(unsigned)off2 + laneoff + 16);

        h2 u[8];
        u[0] = BC(r0.x); u[1] = BC(r0.y); u[2] = BC(r0.z); u[3] = BC(r0.w);
        u[4] = BC(r1.x); u[5] = BC(r1.y); u[6] = BC(r1.z); u[7] = BC(r1.w);

        float pp = 0.f;
#pragma unroll
        for (int k = 0; k < 8; ++k) {
            h2 z = u[k] + xr[k];
            z = __builtin_elementwise_max(z, z * c02);
            pp = fmaf((float)z.x, (float)av[k].x, pp);
            pp = fmaf((float)z.y, (float)av[k].y, pp);
        }
        pp += dpp_mov_f32<0xB1>(pp);                  // quad xor 1
        pp += dpp_mov_f32<0x4E>(pp);                  // quad xor 2 -> head score in quad
        if (base + e >= e1) pp = NEGBIG;              // unmatched slot edge

        if (__any(pp > m + 11.541560f)) {             // 8 * log2(e)
            float mn = fmaxf(m, pp);
            float f  = exp2f(m - mn);
            float w  = exp2f(pp - mn);
#pragma unroll
            for (int k = 0; k < 8; ++k) {
                ac[2 * k]     = fmaf((float)u[k].x, w, ac[2 * k] * f);
                ac[2 * k + 1] = fmaf((float)u[k].y, w, ac[2 * k + 1] * f);
            }
            s = s * f + w;
            m = mn;
        } else {
            float w = exp2f(pp - m);                  // bounded by e^8
#pragma unroll
            for (int k = 0; k < 8; ++k) {
                ac[2 * k]     = fmaf((float)u[k].x, w, ac[2 * k]);
                ac[2 * k + 1] = fmaf((float)u[k].y, w, ac[2 * k + 1]);
            }
            s += w;
        }
    }

    // ---- merge the 4 edge slots (proper online-softmax state merge), 2 stages ----
    {
        float m2 = __shfl_xor(m, 16, 64);
        float s2 = __shfl_xor(s, 16, 64);
        float M  = fmaxf(m, m2);
        float f0 = exp2f(m - M), f1 = exp2f(m2 - M);
#pragma unroll
        for (int k = 0; k < 16; ++k)
            ac[k] = ac[k] * f0 + __shfl_xor(ac[k], 16, 64) * f1;
        s = s * f0 + s2 * f1;
        m = M;
    }
    {
        float m2 = __shfl_xor(m, 32, 64);
        float s2 = __shfl_xor(s, 32, 64);
        float M  = fmaxf(m, m2);
        float f0 = exp2f(m - M), f1 = exp2f(m2 - M);
#pragma unroll
        for (int k = 0; k < 16; ++k)
            ac[k] = ac[k] * f0 + __shfl_xor(ac[k], 32, 64) * f1;
        s = s * f0 + s2 * f1;
        m = M;
    }
    float inv = 1.0f / s;
#pragma unroll
    for (int k = 0; k < 16; ++k) ac[k] *= inv;
    // head mean: out channel c = 16*(j&3)+k; heads on lanes j^4, j^8
#pragma unroll
    for (int k = 0; k < 16; ++k) ac[k] += __shfl_xor(ac[k], 4, 64);
#pragma unroll
    for (int k = 0; k < 16; ++k) ac[k] += __shfl_xor(ac[k], 8, 64);

    if (l < 4) {                                      // lane l covers out channels 16l..16l+15
        const float* gp = gbias + l * 16;
        float o[16];
#pragma unroll
        for (int k = 0; k < 16; ++k) {
            float t = ac[k] * 0.25f + gp[k];
            o[k] = (t > 0.f) ? t : exp2f(t * LOG2E) - 1.f;   // ELU
        }
        if (h_res) {
            const float* rp = h_res + (size_t)node * 64 + l * 16;
#pragma unroll
            for (int k = 0; k < 16; ++k) o[k] += rp[k];
        }
        float* op = h_out + (size_t)node * 64 + l * 16;
#pragma unroll
        for (int k = 0; k < 4; ++k)
            *(float4*)(op + 4 * k) = make_float4(o[4 * k], o[4 * k + 1], o[4 * k + 2], o[4 * k + 3]);
        // fp16 copy for next layer's MFMA GEMM
        uint4 pk0, pk1;
        __half2 t0, t1;
        t0 = __float22half2_rn(make_float2(o[0], o[1]));  pk0.x = *(unsigned*)&t0;
        t1 = __float22half2_rn(make_float2(o[2], o[3]));  pk0.y = *(unsigned*)&t1;
        t0 = __float22half2_rn(make_float2(o[4], o[5]));  pk0.z = *(unsigned*)&t0;
        t1 = __float22half2_rn(make_float2(o[6], o[7]));  pk0.w = *(unsigned*)&t1;
        t0 = __float22half2_rn(make_float2(o[8], o[9]));  pk1.x = *(unsigned*)&t0;
        t1 = __float22half2_rn(make_float2(o[10], o[11])); pk1.y = *(unsigned*)&t1;
        t0 = __float22half2_rn(make_float2(o[12], o[13])); pk1.z = *(unsigned*)&t0;
        t1 = __float22half2_rn(make_float2(o[14], o[15])); pk1.w = *(unsigned*)&t1;
        char* hp = (char*)h16_out + (size_t)node * 128 + l * 32;
        *(uint4*)hp        = pk0;
        *(uint4*)(hp + 16) = pk1;
    }
}

// ---------------- column mean of h over all nodes ----------------
__global__ __launch_bounds__(256) void col_sum(const float* __restrict__ h,
                                               float* __restrict__ gsum, int n) {
    int col = threadIdx.x & 63;
    int sub = threadIdx.x >> 6;   // 0..3
    float s = 0.f;
    for (int r = blockIdx.x * 4 + sub; r < n; r += gridDim.x * 4)
        s += h[(size_t)r * 64 + col];
    __shared__ float tmp[4][64];
    tmp[sub][col] = s;
    __syncthreads();
    if (threadIdx.x < 64) {
        int t = threadIdx.x;
        atomicAdd(&gsum[t], tmp[0][t] + tmp[1][t] + tmp[2][t] + tmp[3][t]);
    }
}

// ---------------- output heads, parallel: blocks 0-8 move, 9 price, 10 value ----------
__global__ __launch_bounds__(128) void heads_kernel(const float* __restrict__ h,
                                                    const float* __restrict__ gsum,
                                                    const int* __restrict__ cur_pos,
                                                    const int* __restrict__ valid,
                                                    const int* __restrict__ owned,
                                                    const float* __restrict__ Wm1, const float* __restrict__ bm1,
                                                    const float* __restrict__ Wm2, const float* __restrict__ bm2,
                                                    const float* __restrict__ Wp,  const float* __restrict__ bp,
                                                    const float* __restrict__ Wv1, const float* __restrict__ bv1,
                                                    const float* __restrict__ Wv2, const float* __restrict__ bv2,
                                                    float* __restrict__ out, int n) {
    int blk = blockIdx.x;
    int tid = threadIdx.x;
    int pos = cur_pos[0];

    if (blk < 9) {
        int cand = (blk == 0) ? pos : valid[blk - 1];
        const float* hcur  = h + (size_t)pos  * 64;
        const float* hcand = h + (size_t)cand * 64;
        float a = bm1[tid];
#pragma unroll
        for (int k = 0; k < 64; ++k) a += hcur[k]  * Wm1[k * 128 + tid];
#pragma unroll
        for (int k = 0; k < 64; ++k) a += hcand[k] * Wm1[(64 + k) * 128 + tid];
        a = fmaxf(a, 0.f) * Wm2[tid];
#pragma unroll
        for (int o = 1; o < 64; o <<= 1) a += __shfl_xor(a, o, 64);
        __shared__ float red[2];
        if ((tid & 63) == 0) red[tid >> 6] = a;
        __syncthreads();
        if (tid == 0) out[blk] = red[0] + red[1] + bm2[0];
    } else if (blk == 9) {
        if (tid < 30) {
            int i = tid / 3, cc = tid % 3;
            int node = owned[i];
            const float* hn = h + (size_t)node * 64;
            float a = bp[cc];
#pragma unroll
            for (int k = 0; k < 64; ++k) a += hn[k] * Wp[k * 3 + cc];
            out[9 + tid] = a;
        }
    } else {
        float invn = 1.0f / (float)n;
        const float* hcur = h + (size_t)pos * 64;
        float a = 0.f;
        if (tid < 64) {
            a = bv1[tid];
#pragma unroll
            for (int k = 0; k < 64; ++k) a += (gsum[k] * invn) * Wv1[k * 64 + tid];
#pragma unroll
            for (int k = 0; k < 64; ++k) a += hcur[k] * Wv1[(64 + k) * 64 + tid];
            a = fmaxf(a, 0.f) * Wv2[tid];
#pragma unroll
            for (int o = 1; o < 64; o <<= 1) a += __shfl_xor(a, o, 64);
            if (tid == 0) out[39] = a + bv2[0];
        }
    }
}

extern "C" void kernel_launch(void* const* d_in, const int* in_sizes, int n_in,
                              void* d_out, int out_size, void* d_ws, size_t ws_size,
                              hipStream_t stream) {
    const float* nf    = (const float*)d_in[0];
    const int*   ei    = (const int*)d_in[1];
    const int*   cpos  = (const int*)d_in[2];
    const int*   valid = (const int*)d_in[3];
    const int*   owned = (const int*)d_in[4];
    const float* Wl    = (const float*)d_in[5];
    const float* bl    = (const float*)d_in[6];
    const float* Wr    = (const float*)d_in[7];
    const float* br    = (const float*)d_in[8];
    const float* att   = (const float*)d_in[9];
    const float* gbias = (const float*)d_in[10];
    const float* Wm1 = (const float*)d_in[11];
    const float* bm1 = (const float*)d_in[12];
    const float* Wm2 = (const float*)d_in[13];
    const float* bm2 = (const float*)d_in[14];
    const float* Wp  = (const float*)d_in[15];
    const float* bp  = (const float*)d_in[16];
    const float* Wv1 = (const float*)d_in[17];
    const float* bv1 = (const float*)d_in[18];
    const float* Wv2 = (const float*)d_in[19];
    const float* bv2 = (const float*)d_in[20];
    float* out = (float*)d_out;

    int n = in_sizes[0] / 64;      // 50000
    int E = in_sizes[1] / 2;       // 800000
    const int* srcp = ei;
    const int* dstp = ei + E;

    // workspace carve
    char* w = (char*)d_ws;
    auto alloc = [&](size_t bytes) -> char* {
        char* p = w;
        w += (bytes + 255) & ~(size_t)255;
        return p;
    };
    __half* xlh     = (__half*)alloc((size_t)n * NHID * 2);
    __half* xrh     = (__half*)alloc((size_t)n * NHID * 2);
    float* hA       = (float*)alloc((size_t)n * 64 * 4);
    float* hB       = (float*)alloc((size_t)n * 64 * 4);
    __half* h16     = (__half*)alloc((size_t)n * 64 * 2);
    __half* Wfrag   = (__half*)alloc((size_t)LAYERS * 32768 * 2);
    float* gsum     = (float*)alloc(64 * 4);
    int*   row_ptr  = (int*)alloc((size_t)(n + 1) * 4);
    int*   row_fill = (int*)alloc((size_t)n * 4);
    int*   col_src  = (int*)alloc((size_t)(E + n + 16) * 4);
    int*   partials = (int*)alloc(256 * 4);

    int nblk = (n + 255) / 256;    // 196
    int nthr = E + n;              // edges + self loops

    // ---- CSR by dst (self loops included; col_src holds byte row offsets) ----
    hipMemsetAsync(row_fill, 0, (size_t)n * 4, stream);
    count_deg<<<(nthr + 255) / 256, 256, 0, stream>>>(dstp, row_fill, E, n);
    scan_partial<<<nblk, 256, 0, stream>>>(row_fill, row_ptr, partials, n);
    scan_partials_scan<<<1, 256, 0, stream>>>(partials, row_ptr, nblk, n);
    scan_add_offsets2<<<nblk, 256, 0, stream>>>(row_ptr, row_fill, partials, n);
    scatter_edges<<<(nthr + 255) / 256, 256, 0, stream>>>(srcp, dstp, row_fill, col_src, E, n);
    hipMemsetAsync(col_src + E + n, 0, 16 * 4, stream);  // pad for slot prefetch

    // ---- weight fragments + initial h16 ----
    wprep<<<LAYERS * 16, 256, 0, stream>>>(Wl, Wr, Wfrag);
    conv_h16<<<(n * 64 + 255) / 256, 256, 0, stream>>>(nf, h16, n * 64);

    // ---- 5 GATv2 layers ----
    const float* hin = nf;
    float* hnext = hB;
    for (int i = 0; i < LAYERS; ++i) {
        gemm_mfma<<<(n + 63) / 64, 256, 0, stream>>>(h16, Wfrag + (size_t)i * 32768,
                                                     bl + i * 256, br + i * 256,
                                                     xlh, xrh, n);
        const float* res = (i == 0) ? nullptr : hin;
        float* outp = (i == 0) ? hA : hnext;
        gat_node<<<(n + 3) / 4, 256, 0, stream>>>(xlh, xrh, row_ptr, col_src,
                                                  att + i * HEADS * 64, gbias + i * 64,
                                                  res, outp, h16, n);
        if (i == 0) {
            hin = hA; hnext = hB;
        } else {
            const float* t = hin;
            hin = outp;
            hnext = (float*)t;
        }
    }

    // ---- heads ----
    hipMemsetAsync(gsum, 0, 64 * 4, stream);
    col_sum<<<256, 256, 0, stream>>>(hin, gsum, n);
    heads_kernel<<<11, 128, 0, stream>>>(hin, gsum, cpos, valid, owned,
                                         Wm1, bm1, Wm2, bm2, Wp, bp,
                                         Wv1, bv1, Wv2, bv2, out, n);
}

// Round 25
// 650.355 us; speedup vs baseline: 1.1452x; 1.1452x over previous
//
#include <hip/hip_runtime.h>
#include <hip/hip_bf16.h>
#include <hip/hip_fp16.h>

#define NHID 256   // HEADS*H
#define HDIM 64
#define HEADS 4
#define LAYERS 5
#define LOG2E 1.4426950408889634f

using half8 = __attribute__((ext_vector_type(8))) _Float16;
using h2    = __attribute__((ext_vector_type(2))) _Float16;
using f32x4 = __attribute__((ext_vector_type(4))) float;

// ---------------- CSR build (self-loops included: grid covers E+n) ----------------
__global__ void count_deg(const int* __restrict__ dst, int* __restrict__ counts, int E, int n) {
    int i = blockIdx.x * blockDim.x + threadIdx.x;
    if (i < E) atomicAdd(&counts[dst[i]], 1);
    else if (i < E + n) atomicAdd(&counts[i - E], 1);   // self loop
}

__global__ __launch_bounds__(256) void scan_partial(const int* __restrict__ counts,
                                                    int* __restrict__ out,
                                                    int* __restrict__ partials, int n) {
    __shared__ int buf[256];
    int tid = threadIdx.x;
    int i = blockIdx.x * 256 + tid;
    int v = (i < n) ? counts[i] : 0;
    buf[tid] = v;
    __syncthreads();
    for (int o = 1; o < 256; o <<= 1) {
        int t = (tid >= o) ? buf[tid - o] : 0;
        __syncthreads();
        buf[tid] += t;
        __syncthreads();
    }
    if (i < n) out[i] = buf[tid] - v;              // exclusive within chunk
    if (tid == 255) partials[blockIdx.x] = buf[255];
}

__global__ __launch_bounds__(256) void scan_partials_scan(int* __restrict__ partials,
                                                          int* __restrict__ out,
                                                          int nblk, int n) {
    __shared__ int buf[256];
    int tid = threadIdx.x;
    int v = (tid < nblk) ? partials[tid] : 0;
    buf[tid] = v;
    __syncthreads();
    for (int o = 1; o < 256; o <<= 1) {
        int t = (tid >= o) ? buf[tid - o] : 0;
        __syncthreads();
        buf[tid] += t;
        __syncthreads();
    }
    if (tid < nblk) partials[tid] = buf[tid] - v;  // exclusive chunk offsets
    if (tid == 255) out[n] = buf[255];
}

// phase 3: add chunk offset; writes BOTH row_ptr and row_fill (saves a copy pass)
__global__ __launch_bounds__(256) void scan_add_offsets2(int* __restrict__ out,
                                                         int* __restrict__ out2,
                                                         const int* __restrict__ partials, int n) {
    int i = blockIdx.x * 256 + threadIdx.x;
    if (i < n) {
        int v = out[i] + partials[blockIdx.x];
        out[i] = v;
        out2[i] = v;
    }
}

// scatter: col_src holds PRE-SHIFTED byte row offsets (src * 512)
__global__ void scatter_edges(const int* __restrict__ src, const int* __restrict__ dst,
                              int* __restrict__ row_fill, int* __restrict__ col_src, int E, int n) {
    int i = blockIdx.x * blockDim.x + threadIdx.x;
    if (i < E) {
        int p = atomicAdd(&row_fill[dst[i]], 1);
        col_src[p] = src[i] << 9;
    } else if (i < E + n) {
        int node = i - E;
        int p = atomicAdd(&row_fill[node], 1);
        col_src[p] = node << 9;                     // self loop
    }
}

// ---------------- W -> fp16 MFMA B-fragment layout ----------------
// Wfrag[layer][t(32)][kh(2)][lane(64)][8]: lane l, elem j: k = kh*32+(l>>4)*8+j,
// col = t*16+(l&15); col<256 -> Wl, else Wr. 32768 halves per layer.
__global__ __launch_bounds__(256) void wprep(const float* __restrict__ Wl,
                                             const float* __restrict__ Wr,
                                             __half* __restrict__ Wfrag) {
    int layer = blockIdx.x >> 4;
    int idx = (blockIdx.x & 15) * 256 + threadIdx.x;  // 0..4095
    int t = idx >> 7, kh = (idx >> 6) & 1, lane = idx & 63;
    const float* WlL = Wl + (size_t)layer * 64 * 256;
    const float* WrL = Wr + (size_t)layer * 64 * 256;
    int col = t * 16 + (lane & 15);
    __half* outp = Wfrag + (size_t)layer * 32768 + ((size_t)(t * 2 + kh) * 64 + lane) * 8;
#pragma unroll
    for (int j = 0; j < 8; ++j) {
        int k = kh * 32 + (lane >> 4) * 8 + j;
        float v = (col < 256) ? WlL[k * 256 + col] : WrL[k * 256 + (col - 256)];
        outp[j] = __float2half(v);
    }
}

// ---------------- convert node features to fp16 ----------------
__global__ void conv_h16(const float* __restrict__ h, __half* __restrict__ h16, int total) {
    int i = blockIdx.x * blockDim.x + threadIdx.x;
    if (i < total) h16[i] = __float2half(h[i]);
}

// ---------------- MFMA GEMM pair (R18 layout): A = h rows, B = Wfrag ----
__global__ __launch_bounds__(256) void gemm_mfma(const __half* __restrict__ h16,
                                                 const __half* __restrict__ Wfrag,
                                                 const float* __restrict__ bl,
                                                 const float* __restrict__ br,
                                                 __half* __restrict__ xlh,
                                                 __half* __restrict__ xrh, int n) {
    int w = threadIdx.x >> 6, l = threadIdx.x & 63;
    int row0 = blockIdx.x * 64 + w * 16;
    if (row0 >= n) return;
    int arow = row0 + (l & 15);
    half8 A0 = *(const half8*)(h16 + (size_t)arow * 64 + (l >> 4) * 8);        // k 0..31
    half8 A1 = *(const half8*)(h16 + (size_t)arow * 64 + 32 + (l >> 4) * 8);   // k 32..63
    int orow = row0 + (l >> 4) * 4;
#pragma unroll
    for (int t = 0; t < 32; ++t) {
        half8 B0 = *(const half8*)(Wfrag + ((size_t)(t * 2 + 0) * 64 + l) * 8);
        half8 B1 = *(const half8*)(Wfrag + ((size_t)(t * 2 + 1) * 64 + l) * 8);
        f32x4 acc = {0.f, 0.f, 0.f, 0.f};
        acc = __builtin_amdgcn_mfma_f32_16x16x32_f16(A0, B0, acc, 0, 0, 0);
        acc = __builtin_amdgcn_mfma_f32_16x16x32_f16(A1, B1, acc, 0, 0, 0);
        int col = t * 16 + (l & 15);
        if (col < 256) {
            float b = bl[col];
#pragma unroll
            for (int j = 0; j < 4; ++j)
                xlh[(size_t)(orow + j) * 256 + col] = __float2half(acc[j] + b);
        } else {
            float b = br[col - 256];
#pragma unroll
            for (int j = 0; j < 4; ++j)
                xrh[(size_t)(orow + j) * 256 + (col - 256)] = __float2half(acc[j] + b);
        }
    }
}

// ---------------- DPP helper ----------------
template <int CTRL>
__device__ __forceinline__ float dpp_mov_f32(float x) {
    return __int_as_float(__builtin_amdgcn_update_dpp(0, __float_as_int(x), CTRL, 0xf, 0xf, false));
}

// ---------------- fused GATv2: 1 wave/node, 2 EDGES per iteration (R23 version) ----
// lanes 0-31: even edge, lanes 32-63: odd edge. Lane owns 8 fp16 channels (16B):
// ll=l&31, head=ll>>3, channel octet=ll&7. Dummy tail edge scored -1e30 (finite).
__global__ __launch_bounds__(256) void gat_node(const __half* __restrict__ xlh,
                                                const __half* __restrict__ xrh,
                                                const int* __restrict__ row_ptr,
                                                const int* __restrict__ col_src,
                                                const float* __restrict__ att,     // [4][64] this layer
                                                const float* __restrict__ gbias,   // [64] this layer
                                                const float* __restrict__ h_res,   // residual or null
                                                float* __restrict__ h_out,
                                                __half* __restrict__ h16_out, int n) {
    int wid  = threadIdx.x >> 6;
    int l    = threadIdx.x & 63;
    int node = blockIdx.x * 4 + wid;
    if (node >= n) return;
    int ll   = l & 31;
    bool hi  = l >= 32;
    int laneoff = ll << 4;                  // 16B per lane within 512B row

    const char* xlb = (const char*)xlh;
    uint4 xrp = *(const uint4*)((const char*)xrh + (size_t)node * 512 + laneoff);
    h2 xr0 = __builtin_bit_cast(h2, xrp.x);
    h2 xr1 = __builtin_bit_cast(h2, xrp.y);
    h2 xr2 = __builtin_bit_cast(h2, xrp.z);
    h2 xr3 = __builtin_bit_cast(h2, xrp.w);

    const float* ap = att + (ll >> 3) * 64 + (ll & 7) * 8;
    float4 avA = *(const float4*)ap;
    float4 avB = *(const float4*)(ap + 4);
    avA.x *= LOG2E; avA.y *= LOG2E; avA.z *= LOG2E; avA.w *= LOG2E;
    avB.x *= LOG2E; avB.y *= LOG2E; avB.z *= LOG2E; avB.w *= LOG2E;

    h2 c02 = {(_Float16)0.2f, (_Float16)0.2f};
    const float NEGBIG = -1.0e30f;
    float m = NEGBIG, s = 0.f;
    float a0=0.f,a1=0.f,a2=0.f,a3=0.f,a4=0.f,a5=0.f,a6=0.f,a7=0.f;

    int e0 = row_ptr[node], e1 = row_ptr[node + 1];   // deg >= 1 (self loop)
    int2 cA = *(const int2*)(col_src + e0);
    uint4 xa = *(const uint4*)(xlb + (size_t)(unsigned)(hi ? cA.y : cA.x) + laneoff);
    int2 cB = *(const int2*)(col_src + e0 + 2);
    uint4 xb = *(const uint4*)(xlb + (size_t)(unsigned)(hi ? cB.y : cB.x) + laneoff);

    for (int idx = e0; idx < e1; idx += 2) {
        uint4 raw = xa;
        xa = xb;
        int2 cz = *(const int2*)(col_src + idx + 4);
        xb = *(const uint4*)(xlb + (size_t)(unsigned)(hi ? cz.y : cz.x) + laneoff);

        h2 u0 = __builtin_bit_cast(h2, raw.x);
        h2 u1 = __builtin_bit_cast(h2, raw.y);
        h2 u2 = __builtin_bit_cast(h2, raw.z);
        h2 u3 = __builtin_bit_cast(h2, raw.w);
        h2 z0 = u0 + xr0, z1 = u1 + xr1, z2 = u2 + xr2, z3 = u3 + xr3;
        z0 = __builtin_elementwise_max(z0, z0 * c02);
        z1 = __builtin_elementwise_max(z1, z1 * c02);
        z2 = __builtin_elementwise_max(z2, z2 * c02);
        z3 = __builtin_elementwise_max(z3, z3 * c02);

        float pp;                                     // log2-domain score (partial)
        pp =  (float)z0.x * avA.x;
        pp = fmaf((float)z0.y, avA.y, pp);
        pp = fmaf((float)z1.x, avA.z, pp);
        pp = fmaf((float)z1.y, avA.w, pp);
        pp = fmaf((float)z2.x, avB.x, pp);
        pp = fmaf((float)z2.y, avB.y, pp);
        pp = fmaf((float)z3.x, avB.z, pp);
        pp = fmaf((float)z3.y, avB.w, pp);
        // 8-lane (per edge, per head) reduce — all-DPP (no DS pipe)
        pp += dpp_mov_f32<0xB1>(pp);                  // quad_perm xor 1
        pp += dpp_mov_f32<0x4E>(pp);                  // quad_perm xor 2
        pp += dpp_mov_f32<0x141>(pp);                 // row_half_mirror: quad 0 <-> 1 of each 8
        if (hi && (idx + 1 >= e1)) pp = NEGBIG;       // dummy tail edge -> annihilated

        if (__any(pp > m + 11.541560f)) {             // 8 * log2(e)
            float mn = fmaxf(m, pp);
            float f  = exp2f(m - mn);
            float w  = exp2f(pp - mn);
            a0 = fmaf((float)u0.x, w, a0 * f); a1 = fmaf((float)u0.y, w, a1 * f);
            a2 = fmaf((float)u1.x, w, a2 * f); a3 = fmaf((float)u1.y, w, a3 * f);
            a4 = fmaf((float)u2.x, w, a4 * f); a5 = fmaf((float)u2.y, w, a5 * f);
            a6 = fmaf((float)u3.x, w, a6 * f); a7 = fmaf((float)u3.y, w, a7 * f);
            s = s * f + w;
            m = mn;
        } else {
            float w = exp2f(pp - m);                  // bounded by e^8
            a0 = fmaf((float)u0.x, w, a0); a1 = fmaf((float)u0.y, w, a1);
            a2 = fmaf((float)u1.x, w, a2); a3 = fmaf((float)u1.y, w, a3);
            a4 = fmaf((float)u2.x, w, a4); a5 = fmaf((float)u2.y, w, a5);
            a6 = fmaf((float)u3.x, w, a6); a7 = fmaf((float)u3.y, w, a7);
            s += w;
        }
    }

    // merge parity halves (lanes l <-> l^32): proper online-softmax state merge
    float m2 = __shfl_xor(m, 32, 64);
    float s2 = __shfl_xor(s, 32, 64);
    float M  = fmaxf(m, m2);
    float f0 = exp2f(m - M), f1 = exp2f(m2 - M);
    float v0 = a0 * f0 + __shfl_xor(a0, 32, 64) * f1;
    float v1 = a1 * f0 + __shfl_xor(a1, 32, 64) * f1;
    float v2 = a2 * f0 + __shfl_xor(a2, 32, 64) * f1;
    float v3 = a3 * f0 + __shfl_xor(a3, 32, 64) * f1;
    float v4 = a4 * f0 + __shfl_xor(a4, 32, 64) * f1;
    float v5 = a5 * f0 + __shfl_xor(a5, 32, 64) * f1;
    float v6 = a6 * f0 + __shfl_xor(a6, 32, 64) * f1;
    float v7 = a7 * f0 + __shfl_xor(a7, 32, 64) * f1;
    float sT = s * f0 + s2 * f1;
    float inv = 1.0f / sT;
    v0 *= inv; v1 *= inv; v2 *= inv; v3 *= inv;
    v4 *= inv; v5 *= inv; v6 *= inv; v7 *= inv;
    // sum over heads: lanes ll, ll^8, ll^16, ll^24
    v0 += __shfl_xor(v0, 8, 64); v1 += __shfl_xor(v1, 8, 64);
    v2 += __shfl_xor(v2, 8, 64); v3 += __shfl_xor(v3, 8, 64);
    v4 += __shfl_xor(v4, 8, 64); v5 += __shfl_xor(v5, 8, 64);
    v6 += __shfl_xor(v6, 8, 64); v7 += __shfl_xor(v7, 8, 64);
    v0 += __shfl_xor(v0, 16, 64); v1 += __shfl_xor(v1, 16, 64);
    v2 += __shfl_xor(v2, 16, 64); v3 += __shfl_xor(v3, 16, 64);
    v4 += __shfl_xor(v4, 16, 64); v5 += __shfl_xor(v5, 16, 64);
    v6 += __shfl_xor(v6, 16, 64); v7 += __shfl_xor(v7, 16, 64);

    if (l < 8) {                                      // lane l owns channels 8l..8l+7
        const float* gp = gbias + l * 8;
        float4 gA = *(const float4*)gp;
        float4 gB = *(const float4*)(gp + 4);
        float o0 = v0 * 0.25f + gA.x, o1 = v1 * 0.25f + gA.y;
        float o2 = v2 * 0.25f + gA.z, o3 = v3 * 0.25f + gA.w;
        float o4 = v4 * 0.25f + gB.x, o5 = v5 * 0.25f + gB.y;
        float o6 = v6 * 0.25f + gB.z, o7 = v7 * 0.25f + gB.w;
        o0 = (o0 > 0.f) ? o0 : exp2f(o0 * LOG2E) - 1.f;
        o1 = (o1 > 0.f) ? o1 : exp2f(o1 * LOG2E) - 1.f;
        o2 = (o2 > 0.f) ? o2 : exp2f(o2 * LOG2E) - 1.f;
        o3 = (o3 > 0.f) ? o3 : exp2f(o3 * LOG2E) - 1.f;
        o4 = (o4 > 0.f) ? o4 : exp2f(o4 * LOG2E) - 1.f;
        o5 = (o5 > 0.f) ? o5 : exp2f(o5 * LOG2E) - 1.f;
        o6 = (o6 > 0.f) ? o6 : exp2f(o6 * LOG2E) - 1.f;
        o7 = (o7 > 0.f) ? o7 : exp2f(o7 * LOG2E) - 1.f;
        if (h_res) {
            const float* rp = h_res + (size_t)node * 64 + l * 8;
            float4 rA = *(const float4*)rp;
            float4 rB = *(const float4*)(rp + 4);
            o0 += rA.x; o1 += rA.y; o2 += rA.z; o3 += rA.w;
            o4 += rB.x; o5 += rB.y; o6 += rB.z; o7 += rB.w;
        }
        float* op = h_out + (size_t)node * 64 + l * 8;
        *(float4*)op       = make_float4(o0, o1, o2, o3);
        *(float4*)(op + 4) = make_float4(o4, o5, o6, o7);
        __half2 p0 = __float22half2_rn(make_float2(o0, o1));
        __half2 p1 = __float22half2_rn(make_float2(o2, o3));
        __half2 p2 = __float22half2_rn(make_float2(o4, o5));
        __half2 p3 = __float22half2_rn(make_float2(o6, o7));
        uint4 pk;
        pk.x = *(unsigned*)&p0; pk.y = *(unsigned*)&p1;
        pk.z = *(unsigned*)&p2; pk.w = *(unsigned*)&p3;
        *(uint4*)((char*)h16_out + (size_t)node * 128 + l * 16) = pk;
    }
}

// ---------------- column mean of h over all nodes ----------------
__global__ __launch_bounds__(256) void col_sum(const float* __restrict__ h,
                                               float* __restrict__ gsum, int n) {
    int col = threadIdx.x & 63;
    int sub = threadIdx.x >> 6;   // 0..3
    float s = 0.f;
    for (int r = blockIdx.x * 4 + sub; r < n; r += gridDim.x * 4)
        s += h[(size_t)r * 64 + col];
    __shared__ float tmp[4][64];
    tmp[sub][col] = s;
    __syncthreads();
    if (threadIdx.x < 64) {
        int t = threadIdx.x;
        atomicAdd(&gsum[t], tmp[0][t] + tmp[1][t] + tmp[2][t] + tmp[3][t]);
    }
}

// ---------------- output heads, parallel: blocks 0-8 move, 9 price, 10 value ----------
__global__ __launch_bounds__(128) void heads_kernel(const float* __restrict__ h,
                                                    const float* __restrict__ gsum,
                                                    const int* __restrict__ cur_pos,
                                                    const int* __restrict__ valid,
                                                    const int* __restrict__ owned,
                                                    const float* __restrict__ Wm1, const float* __restrict__ bm1,
                                                    const float* __restrict__ Wm2, const float* __restrict__ bm2,
                                                    const float* __restrict__ Wp,  const float* __restrict__ bp,
                                                    const float* __restrict__ Wv1, const float* __restrict__ bv1,
                                                    const float* __restrict__ Wv2, const float* __restrict__ bv2,
                                                    float* __restrict__ out, int n) {
    int blk = blockIdx.x;
    int tid = threadIdx.x;
    int pos = cur_pos[0];

    if (blk < 9) {
        int cand = (blk == 0) ? pos : valid[blk - 1];
        const float* hcur  = h + (size_t)pos  * 64;
        const float* hcand = h + (size_t)cand * 64;
        float a = bm1[tid];
#pragma unroll
        for (int k = 0; k < 64; ++k) a += hcur[k]  * Wm1[k * 128 + tid];
#pragma unroll
        for (int k = 0; k < 64; ++k) a += hcand[k] * Wm1[(64 + k) * 128 + tid];
        a = fmaxf(a, 0.f) * Wm2[tid];
#pragma unroll
        for (int o = 1; o < 64; o <<= 1) a += __shfl_xor(a, o, 64);
        __shared__ float red[2];
        if ((tid & 63) == 0) red[tid >> 6] = a;
        __syncthreads();
        if (tid == 0) out[blk] = red[0] + red[1] + bm2[0];
    } else if (blk == 9) {
        if (tid < 30) {
            int i = tid / 3, cc = tid % 3;
            int node = owned[i];
            const float* hn = h + (size_t)node * 64;
            float a = bp[cc];
#pragma unroll
            for (int k = 0; k < 64; ++k) a += hn[k] * Wp[k * 3 + cc];
            out[9 + tid] = a;
        }
    } else {
        float invn = 1.0f / (float)n;
        const float* hcur = h + (size_t)pos * 64;
        float a = 0.f;
        if (tid < 64) {
            a = bv1[tid];
#pragma unroll
            for (int k = 0; k < 64; ++k) a += (gsum[k] * invn) * Wv1[k * 64 + tid];
#pragma unroll
            for (int k = 0; k < 64; ++k) a += hcur[k] * Wv1[(64 + k) * 64 + tid];
            a = fmaxf(a, 0.f) * Wv2[tid];
#pragma unroll
            for (int o = 1; o < 64; o <<= 1) a += __shfl_xor(a, o, 64);
            if (tid == 0) out[39] = a + bv2[0];
        }
    }
}

extern "C" void kernel_launch(void* const* d_in, const int* in_sizes, int n_in,
                              void* d_out, int out_size, void* d_ws, size_t ws_size,
                              hipStream_t stream) {
    const float* nf    = (const float*)d_in[0];
    const int*   ei    = (const int*)d_in[1];
    const int*   cpos  = (const int*)d_in[2];
    const int*   valid = (const int*)d_in[3];
    const int*   owned = (const int*)d_in[4];
    const float* Wl    = (const float*)d_in[5];
    const float* bl    = (const float*)d_in[6];
    const float* Wr    = (const float*)d_in[7];
    const float* br    = (const float*)d_in[8];
    const float* att   = (const float*)d_in[9];
    const float* gbias = (const float*)d_in[10];
    const float* Wm1 = (const float*)d_in[11];
    const float* bm1 = (const float*)d_in[12];
    const float* Wm2 = (const float*)d_in[13];
    const float* bm2 = (const float*)d_in[14];
    const float* Wp  = (const float*)d_in[15];
    const float* bp  = (const float*)d_in[16];
    const float* Wv1 = (const float*)d_in[17];
    const float* bv1 = (const float*)d_in[18];
    const float* Wv2 = (const float*)d_in[19];
    const float* bv2 = (const float*)d_in[20];
    float* out = (float*)d_out;

    int n = in_sizes[0] / 64;      // 50000
    int E = in_sizes[1] / 2;       // 800000
    const int* srcp = ei;
    const int* dstp = ei + E;

    // workspace carve
    char* w = (char*)d_ws;
    auto alloc = [&](size_t bytes) -> char* {
        char* p = w;
        w += (bytes + 255) & ~(size_t)255;
        return p;
    };
    __half* xlh     = (__half*)alloc((size_t)n * NHID * 2);
    __half* xrh     = (__half*)alloc((size_t)n * NHID * 2);
    float* hA       = (float*)alloc((size_t)n * 64 * 4);
    float* hB       = (float*)alloc((size_t)n * 64 * 4);
    __half* h16     = (__half*)alloc((size_t)n * 64 * 2);
    __half* Wfrag   = (__half*)alloc((size_t)LAYERS * 32768 * 2);
    float* gsum     = (float*)alloc(64 * 4);
    int*   row_ptr  = (int*)alloc((size_t)(n + 1) * 4);
    int*   row_fill = (int*)alloc((size_t)n * 4);
    int*   col_src  = (int*)alloc((size_t)(E + n + 16) * 4);
    int*   partials = (int*)alloc(256 * 4);

    int nblk = (n + 255) / 256;    // 196
    int nthr = E + n;              // edges + self loops

    // ---- CSR by dst (self loops included; col_src holds byte row offsets) ----
    hipMemsetAsync(row_fill, 0, (size_t)n * 4, stream);
    count_deg<<<(nthr + 255) / 256, 256, 0, stream>>>(dstp, row_fill, E, n);
    scan_partial<<<nblk, 256, 0, stream>>>(row_fill, row_ptr, partials, n);
    scan_partials_scan<<<1, 256, 0, stream>>>(partials, row_ptr, nblk, n);
    scan_add_offsets2<<<nblk, 256, 0, stream>>>(row_ptr, row_fill, partials, n);
    scatter_edges<<<(nthr + 255) / 256, 256, 0, stream>>>(srcp, dstp, row_fill, col_src, E, n);
    hipMemsetAsync(col_src + E + n, 0, 16 * 4, stream);  // pad for pair prefetch

    // ---- weight fragments + initial h16 ----
    wprep<<<LAYERS * 16, 256, 0, stream>>>(Wl, Wr, Wfrag);
    conv_h16<<<(n * 64 + 255) / 256, 256, 0, stream>>>(nf, h16, n * 64);

    // ---- 5 GATv2 layers ----
    const float* hin = nf;
    float* hnext = hB;
    for (int i = 0; i < LAYERS; ++i) {
        gemm_mfma<<<(n + 63) / 64, 256, 0, stream>>>(h16, Wfrag + (size_t)i * 32768,
                                                     bl + i * 256, br + i * 256,
                                                     xlh, xrh, n);
        const float* res = (i == 0) ? nullptr : hin;
        float* outp = (i == 0) ? hA : hnext;
        gat_node<<<(n + 3) / 4, 256, 0, stream>>>(xlh, xrh, row_ptr, col_src,
                                                  att + i * HEADS * 64, gbias + i * 64,
                                                  res, outp, h16, n);
        if (i == 0) {
            hin = hA; hnext = hB;
        } else {
            const float* t = hin;
            hin = outp;
            hnext = (float*)t;
        }
    }

    // ---- heads ----
    hipMemsetAsync(gsum, 0, 64 * 4, stream);
    col_sum<<<256, 256, 0, stream>>>(hin, gsum, n);
    heads_kernel<<<11, 128, 0, stream>>>(hin, gsum, cpos, valid, owned,
                                         Wm1, bm1, Wm2, bm2, Wp, bp,
                                         Wv1, bv1, Wv2, bv2, out, n);
}

// Round 26
// 636.905 us; speedup vs baseline: 1.1694x; 1.0211x over previous
//
#include <hip/hip_runtime.h>
#include <hip/hip_bf16.h>
#include <hip/hip_fp16.h>

#define NHID 256   // HEADS*H
#define HDIM 64
#define HEADS 4
#define LAYERS 5
#define LOG2E 1.4426950408889634f

using half8 = __attribute__((ext_vector_type(8))) _Float16;
using h2    = __attribute__((ext_vector_type(2))) _Float16;
using f32x4 = __attribute__((ext_vector_type(4))) float;

// ---------------- CSR build (self-loops included: grid covers E+n) ----------------
__global__ void count_deg(const int* __restrict__ dst, int* __restrict__ counts, int E, int n) {
    int i = blockIdx.x * blockDim.x + threadIdx.x;
    if (i < E) atomicAdd(&counts[dst[i]], 1);
    else if (i < E + n) atomicAdd(&counts[i - E], 1);   // self loop
}

__global__ __launch_bounds__(256) void scan_partial(const int* __restrict__ counts,
                                                    int* __restrict__ out,
                                                    int* __restrict__ partials, int n) {
    __shared__ int buf[256];
    int tid = threadIdx.x;
    int i = blockIdx.x * 256 + tid;
    int v = (i < n) ? counts[i] : 0;
    buf[tid] = v;
    __syncthreads();
    for (int o = 1; o < 256; o <<= 1) {
        int t = (tid >= o) ? buf[tid - o] : 0;
        __syncthreads();
        buf[tid] += t;
        __syncthreads();
    }
    if (i < n) out[i] = buf[tid] - v;              // exclusive within chunk
    if (tid == 255) partials[blockIdx.x] = buf[255];
}

__global__ __launch_bounds__(256) void scan_partials_scan(int* __restrict__ partials,
                                                          int* __restrict__ out,
                                                          int nblk, int n) {
    __shared__ int buf[256];
    int tid = threadIdx.x;
    int v = (tid < nblk) ? partials[tid] : 0;
    buf[tid] = v;
    __syncthreads();
    for (int o = 1; o < 256; o <<= 1) {
        int t = (tid >= o) ? buf[tid - o] : 0;
        __syncthreads();
        buf[tid] += t;
        __syncthreads();
    }
    if (tid < nblk) partials[tid] = buf[tid] - v;  // exclusive chunk offsets
    if (tid == 255) out[n] = buf[255];
}

// phase 3: add chunk offset; writes BOTH row_ptr and row_fill (saves a copy pass)
__global__ __launch_bounds__(256) void scan_add_offsets2(int* __restrict__ out,
                                                         int* __restrict__ out2,
                                                         const int* __restrict__ partials, int n) {
    int i = blockIdx.x * 256 + threadIdx.x;
    if (i < n) {
        int v = out[i] + partials[blockIdx.x];
        out[i] = v;
        out2[i] = v;
    }
}

// scatter: col_src holds PRE-SHIFTED byte row offsets (src * 512)
__global__ void scatter_edges(const int* __restrict__ src, const int* __restrict__ dst,
                              int* __restrict__ row_fill, int* __restrict__ col_src, int E, int n) {
    int i = blockIdx.x * blockDim.x + threadIdx.x;
    if (i < E) {
        int p = atomicAdd(&row_fill[dst[i]], 1);
        col_src[p] = src[i] << 9;
    } else if (i < E + n) {
        int node = i - E;
        int p = atomicAdd(&row_fill[node], 1);
        col_src[p] = node << 9;                     // self loop
    }
}

// ---------------- W -> fp16 MFMA B-fragment layout ----------------
// Wfrag[layer][t(32)][kh(2)][lane(64)][8]: lane l, elem j: k = kh*32+(l>>4)*8+j,
// col = t*16+(l&15); col<256 -> Wl, else Wr. 32768 halves per layer.
__global__ __launch_bounds__(256) void wprep(const float* __restrict__ Wl,
                                             const float* __restrict__ Wr,
                                             __half* __restrict__ Wfrag) {
    int layer = blockIdx.x >> 4;
    int idx = (blockIdx.x & 15) * 256 + threadIdx.x;  // 0..4095
    int t = idx >> 7, kh = (idx >> 6) & 1, lane = idx & 63;
    const float* WlL = Wl + (size_t)layer * 64 * 256;
    const float* WrL = Wr + (size_t)layer * 64 * 256;
    int col = t * 16 + (lane & 15);
    __half* outp = Wfrag + (size_t)layer * 32768 + ((size_t)(t * 2 + kh) * 64 + lane) * 8;
#pragma unroll
    for (int j = 0; j < 8; ++j) {
        int k = kh * 32 + (lane >> 4) * 8 + j;
        float v = (col < 256) ? WlL[k * 256 + col] : WrL[k * 256 + (col - 256)];
        outp[j] = __float2half(v);
    }
}

// ---------------- convert node features to fp16 ----------------
__global__ void conv_h16(const float* __restrict__ h, __half* __restrict__ h16, int total) {
    int i = blockIdx.x * blockDim.x + threadIdx.x;
    if (i < total) h16[i] = __float2half(h[i]);
}

// ---------------- MFMA GEMM pair (R18 layout): A = h rows, B = Wfrag ----
__global__ __launch_bounds__(256) void gemm_mfma(const __half* __restrict__ h16,
                                                 const __half* __restrict__ Wfrag,
                                                 const float* __restrict__ bl,
                                                 const float* __restrict__ br,
                                                 __half* __restrict__ xlh,
                                                 __half* __restrict__ xrh, int n) {
    int w = threadIdx.x >> 6, l = threadIdx.x & 63;
    int row0 = blockIdx.x * 64 + w * 16;
    if (row0 >= n) return;
    int arow = row0 + (l & 15);
    half8 A0 = *(const half8*)(h16 + (size_t)arow * 64 + (l >> 4) * 8);        // k 0..31
    half8 A1 = *(const half8*)(h16 + (size_t)arow * 64 + 32 + (l >> 4) * 8);   // k 32..63
    int orow = row0 + (l >> 4) * 4;
#pragma unroll
    for (int t = 0; t < 32; ++t) {
        half8 B0 = *(const half8*)(Wfrag + ((size_t)(t * 2 + 0) * 64 + l) * 8);
        half8 B1 = *(const half8*)(Wfrag + ((size_t)(t * 2 + 1) * 64 + l) * 8);
        f32x4 acc = {0.f, 0.f, 0.f, 0.f};
        acc = __builtin_amdgcn_mfma_f32_16x16x32_f16(A0, B0, acc, 0, 0, 0);
        acc = __builtin_amdgcn_mfma_f32_16x16x32_f16(A1, B1, acc, 0, 0, 0);
        int col = t * 16 + (l & 15);
        if (col < 256) {
            float b = bl[col];
#pragma unroll
            for (int j = 0; j < 4; ++j)
                xlh[(size_t)(orow + j) * 256 + col] = __float2half(acc[j] + b);
        } else {
            float b = br[col - 256];
#pragma unroll
            for (int j = 0; j < 4; ++j)
                xrh[(size_t)(orow + j) * 256 + (col - 256)] = __float2half(acc[j] + b);
        }
    }
}

// ---------------- DPP helper ----------------
template <int CTRL>
__device__ __forceinline__ float dpp_mov_f32(float x) {
    return __int_as_float(__builtin_amdgcn_update_dpp(0, __float_as_int(x), CTRL, 0xf, 0xf, false));
}

// ---------------- fused GATv2: 1 wave/node, 2 EDGES per iteration ----------------
// lanes 0-31: even edge, lanes 32-63: odd edge. Lane owns 8 fp16 channels (16B):
// ll=l&31, head=ll>>3, channel octet=ll&7. Dummy tail edge scored -1e30 (finite).
// Score dot via v_dot2_f32_f16 (4 instrs instead of 8 fma_mix).
__global__ __launch_bounds__(256) void gat_node(const __half* __restrict__ xlh,
                                                const __half* __restrict__ xrh,
                                                const int* __restrict__ row_ptr,
                                                const int* __restrict__ col_src,
                                                const float* __restrict__ att,     // [4][64] this layer
                                                const float* __restrict__ gbias,   // [64] this layer
                                                const float* __restrict__ h_res,   // residual or null
                                                float* __restrict__ h_out,
                                                __half* __restrict__ h16_out, int n) {
    int wid  = threadIdx.x >> 6;
    int l    = threadIdx.x & 63;
    int node = blockIdx.x * 4 + wid;
    if (node >= n) return;
    int ll   = l & 31;
    bool hi  = l >= 32;
    int laneoff = ll << 4;                  // 16B per lane within 512B row

    const char* xlb = (const char*)xlh;
    uint4 xrp = *(const uint4*)((const char*)xrh + (size_t)node * 512 + laneoff);
    h2 xr0 = __builtin_bit_cast(h2, xrp.x);
    h2 xr1 = __builtin_bit_cast(h2, xrp.y);
    h2 xr2 = __builtin_bit_cast(h2, xrp.z);
    h2 xr3 = __builtin_bit_cast(h2, xrp.w);

    const float* ap = att + (ll >> 3) * 64 + (ll & 7) * 8;
    h2 av0 = {(_Float16)(ap[0] * LOG2E), (_Float16)(ap[1] * LOG2E)};
    h2 av1 = {(_Float16)(ap[2] * LOG2E), (_Float16)(ap[3] * LOG2E)};
    h2 av2 = {(_Float16)(ap[4] * LOG2E), (_Float16)(ap[5] * LOG2E)};
    h2 av3 = {(_Float16)(ap[6] * LOG2E), (_Float16)(ap[7] * LOG2E)};

    h2 c02 = {(_Float16)0.2f, (_Float16)0.2f};
    const float NEGBIG = -1.0e30f;
    float m = NEGBIG, s = 0.f;
    float a0=0.f,a1=0.f,a2=0.f,a3=0.f,a4=0.f,a5=0.f,a6=0.f,a7=0.f;

    int e0 = row_ptr[node], e1 = row_ptr[node + 1];   // deg >= 1 (self loop)
    int2 cA = *(const int2*)(col_src + e0);
    uint4 xa = *(const uint4*)(xlb + (size_t)(unsigned)(hi ? cA.y : cA.x) + laneoff);
    int2 cB = *(const int2*)(col_src + e0 + 2);
    uint4 xb = *(const uint4*)(xlb + (size_t)(unsigned)(hi ? cB.y : cB.x) + laneoff);

    for (int idx = e0; idx < e1; idx += 2) {
        uint4 raw = xa;
        xa = xb;
        int2 cz = *(const int2*)(col_src + idx + 4);
        xb = *(const uint4*)(xlb + (size_t)(unsigned)(hi ? cz.y : cz.x) + laneoff);

        h2 u0 = __builtin_bit_cast(h2, raw.x);
        h2 u1 = __builtin_bit_cast(h2, raw.y);
        h2 u2 = __builtin_bit_cast(h2, raw.z);
        h2 u3 = __builtin_bit_cast(h2, raw.w);
        h2 z0 = u0 + xr0, z1 = u1 + xr1, z2 = u2 + xr2, z3 = u3 + xr3;
        z0 = __builtin_elementwise_max(z0, z0 * c02);
        z1 = __builtin_elementwise_max(z1, z1 * c02);
        z2 = __builtin_elementwise_max(z2, z2 * c02);
        z3 = __builtin_elementwise_max(z3, z3 * c02);

        // log2-domain score via v_dot2_f32_f16 chain
        float pp;
        pp = __builtin_amdgcn_fdot2(z0, av0, 0.f, false);
        pp = __builtin_amdgcn_fdot2(z1, av1, pp, false);
        pp = __builtin_amdgcn_fdot2(z2, av2, pp, false);
        pp = __builtin_amdgcn_fdot2(z3, av3, pp, false);
        // 8-lane (per edge, per head) reduce — all-DPP (no DS pipe)
        pp += dpp_mov_f32<0xB1>(pp);                  // quad_perm xor 1
        pp += dpp_mov_f32<0x4E>(pp);                  // quad_perm xor 2
        pp += dpp_mov_f32<0x141>(pp);                 // row_half_mirror: quad 0 <-> 1 of each 8
        if (hi && (idx + 1 >= e1)) pp = NEGBIG;       // dummy tail edge -> annihilated

        if (__any(pp > m + 11.541560f)) {             // 8 * log2(e)
            float mn = fmaxf(m, pp);
            float f  = exp2f(m - mn);
            float w  = exp2f(pp - mn);
            a0 = fmaf((float)u0.x, w, a0 * f); a1 = fmaf((float)u0.y, w, a1 * f);
            a2 = fmaf((float)u1.x, w, a2 * f); a3 = fmaf((float)u1.y, w, a3 * f);
            a4 = fmaf((float)u2.x, w, a4 * f); a5 = fmaf((float)u2.y, w, a5 * f);
            a6 = fmaf((float)u3.x, w, a6 * f); a7 = fmaf((float)u3.y, w, a7 * f);
            s = s * f + w;
            m = mn;
        } else {
            float w = exp2f(pp - m);                  // bounded by e^8
            a0 = fmaf((float)u0.x, w, a0); a1 = fmaf((float)u0.y, w, a1);
            a2 = fmaf((float)u1.x, w, a2); a3 = fmaf((float)u1.y, w, a3);
            a4 = fmaf((float)u2.x, w, a4); a5 = fmaf((float)u2.y, w, a5);
            a6 = fmaf((float)u3.x, w, a6); a7 = fmaf((float)u3.y, w, a7);
            s += w;
        }
    }

    // merge parity halves (lanes l <-> l^32): proper online-softmax state merge
    float m2 = __shfl_xor(m, 32, 64);
    float s2 = __shfl_xor(s, 32, 64);
    float M  = fmaxf(m, m2);
    float f0 = exp2f(m - M), f1 = exp2f(m2 - M);
    float v0 = a0 * f0 + __shfl_xor(a0, 32, 64) * f1;
    float v1 = a1 * f0 + __shfl_xor(a1, 32, 64) * f1;
    float v2 = a2 * f0 + __shfl_xor(a2, 32, 64) * f1;
    float v3 = a3 * f0 + __shfl_xor(a3, 32, 64) * f1;
    float v4 = a4 * f0 + __shfl_xor(a4, 32, 64) * f1;
    float v5 = a5 * f0 + __shfl_xor(a5, 32, 64) * f1;
    float v6 = a6 * f0 + __shfl_xor(a6, 32, 64) * f1;
    float v7 = a7 * f0 + __shfl_xor(a7, 32, 64) * f1;
    float sT = s * f0 + s2 * f1;
    float inv = 1.0f / sT;
    v0 *= inv; v1 *= inv; v2 *= inv; v3 *= inv;
    v4 *= inv; v5 *= inv; v6 *= inv; v7 *= inv;
    // sum over heads: lanes ll, ll^8, ll^16, ll^24
    v0 += __shfl_xor(v0, 8, 64); v1 += __shfl_xor(v1, 8, 64);
    v2 += __shfl_xor(v2, 8, 64); v3 += __shfl_xor(v3, 8, 64);
    v4 += __shfl_xor(v4, 8, 64); v5 += __shfl_xor(v5, 8, 64);
    v6 += __shfl_xor(v6, 8, 64); v7 += __shfl_xor(v7, 8, 64);
    v0 += __shfl_xor(v0, 16, 64); v1 += __shfl_xor(v1, 16, 64);
    v2 += __shfl_xor(v2, 16, 64); v3 += __shfl_xor(v3, 16, 64);
    v4 += __shfl_xor(v4, 16, 64); v5 += __shfl_xor(v5, 16, 64);
    v6 += __shfl_xor(v6, 16, 64); v7 += __shfl_xor(v7, 16, 64);

    if (l < 8) {                                      // lane l owns channels 8l..8l+7
        const float* gp = gbias + l * 8;
        float4 gA = *(const float4*)gp;
        float4 gB = *(const float4*)(gp + 4);
        float o0 = v0 * 0.25f + gA.x, o1 = v1 * 0.25f + gA.y;
        float o2 = v2 * 0.25f + gA.z, o3 = v3 * 0.25f + gA.w;
        float o4 = v4 * 0.25f + gB.x, o5 = v5 * 0.25f + gB.y;
        float o6 = v6 * 0.25f + gB.z, o7 = v7 * 0.25f + gB.w;
        o0 = (o0 > 0.f) ? o0 : exp2f(o0 * LOG2E) - 1.f;
        o1 = (o1 > 0.f) ? o1 : exp2f(o1 * LOG2E) - 1.f;
        o2 = (o2 > 0.f) ? o2 : exp2f(o2 * LOG2E) - 1.f;
        o3 = (o3 > 0.f) ? o3 : exp2f(o3 * LOG2E) - 1.f;
        o4 = (o4 > 0.f) ? o4 : exp2f(o4 * LOG2E) - 1.f;
        o5 = (o5 > 0.f) ? o5 : exp2f(o5 * LOG2E) - 1.f;
        o6 = (o6 > 0.f) ? o6 : exp2f(o6 * LOG2E) - 1.f;
        o7 = (o7 > 0.f) ? o7 : exp2f(o7 * LOG2E) - 1.f;
        if (h_res) {
            const float* rp = h_res + (size_t)node * 64 + l * 8;
            float4 rA = *(const float4*)rp;
            float4 rB = *(const float4*)(rp + 4);
            o0 += rA.x; o1 += rA.y; o2 += rA.z; o3 += rA.w;
            o4 += rB.x; o5 += rB.y; o6 += rB.z; o7 += rB.w;
        }
        float* op = h_out + (size_t)node * 64 + l * 8;
        *(float4*)op       = make_float4(o0, o1, o2, o3);
        *(float4*)(op + 4) = make_float4(o4, o5, o6, o7);
        __half2 p0 = __float22half2_rn(make_float2(o0, o1));
        __half2 p1 = __float22half2_rn(make_float2(o2, o3));
        __half2 p2 = __float22half2_rn(make_float2(o4, o5));
        __half2 p3 = __float22half2_rn(make_float2(o6, o7));
        uint4 pk;
        pk.x = *(unsigned*)&p0; pk.y = *(unsigned*)&p1;
        pk.z = *(unsigned*)&p2; pk.w = *(unsigned*)&p3;
        *(uint4*)((char*)h16_out + (size_t)node * 128 + l * 16) = pk;
    }
}

// ---------------- column mean of h over all nodes ----------------
__global__ __launch_bounds__(256) void col_sum(const float* __restrict__ h,
                                               float* __restrict__ gsum, int n) {
    int col = threadIdx.x & 63;
    int sub = threadIdx.x >> 6;   // 0..3
    float s = 0.f;
    for (int r = blockIdx.x * 4 + sub; r < n; r += gridDim.x * 4)
        s += h[(size_t)r * 64 + col];
    __shared__ float tmp[4][64];
    tmp[sub][col] = s;
    __syncthreads();
    if (threadIdx.x < 64) {
        int t = threadIdx.x;
        atomicAdd(&gsum[t], tmp[0][t] + tmp[1][t] + tmp[2][t] + tmp[3][t]);
    }
}

// ---------------- output heads, parallel: blocks 0-8 move, 9 price, 10 value ----------
__global__ __launch_bounds__(128) void heads_kernel(const float* __restrict__ h,
                                                    const float* __restrict__ gsum,
                                                    const int* __restrict__ cur_pos,
                                                    const int* __restrict__ valid,
                                                    const int* __restrict__ owned,
                                                    const float* __restrict__ Wm1, const float* __restrict__ bm1,
                                                    const float* __restrict__ Wm2, const float* __restrict__ bm2,
                                                    const float* __restrict__ Wp,  const float* __restrict__ bp,
                                                    const float* __restrict__ Wv1, const float* __restrict__ bv1,
                                                    const float* __restrict__ Wv2, const float* __restrict__ bv2,
                                                    float* __restrict__ out, int n) {
    int blk = blockIdx.x;
    int tid = threadIdx.x;
    int pos = cur_pos[0];

    if (blk < 9) {
        int cand = (blk == 0) ? pos : valid[blk - 1];
        const float* hcur  = h + (size_t)pos  * 64;
        const float* hcand = h + (size_t)cand * 64;
        float a = bm1[tid];
#pragma unroll
        for (int k = 0; k < 64; ++k) a += hcur[k]  * Wm1[k * 128 + tid];
#pragma unroll
        for (int k = 0; k < 64; ++k) a += hcand[k] * Wm1[(64 + k) * 128 + tid];
        a = fmaxf(a, 0.f) * Wm2[tid];
#pragma unroll
        for (int o = 1; o < 64; o <<= 1) a += __shfl_xor(a, o, 64);
        __shared__ float red[2];
        if ((tid & 63) == 0) red[tid >> 6] = a;
        __syncthreads();
        if (tid == 0) out[blk] = red[0] + red[1] + bm2[0];
    } else if (blk == 9) {
        if (tid < 30) {
            int i = tid / 3, cc = tid % 3;
            int node = owned[i];
            const float* hn = h + (size_t)node * 64;
            float a = bp[cc];
#pragma unroll
            for (int k = 0; k < 64; ++k) a += hn[k] * Wp[k * 3 + cc];
            out[9 + tid] = a;
        }
    } else {
        float invn = 1.0f / (float)n;
        const float* hcur = h + (size_t)pos * 64;
        float a = 0.f;
        if (tid < 64) {
            a = bv1[tid];
#pragma unroll
            for (int k = 0; k < 64; ++k) a += (gsum[k] * invn) * Wv1[k * 64 + tid];
#pragma unroll
            for (int k = 0; k < 64; ++k) a += hcur[k] * Wv1[(64 + k) * 64 + tid];
            a = fmaxf(a, 0.f) * Wv2[tid];
#pragma unroll
            for (int o = 1; o < 64; o <<= 1) a += __shfl_xor(a, o, 64);
            if (tid == 0) out[39] = a + bv2[0];
        }
    }
}

extern "C" void kernel_launch(void* const* d_in, const int* in_sizes, int n_in,
                              void* d_out, int out_size, void* d_ws, size_t ws_size,
                              hipStream_t stream) {
    const float* nf    = (const float*)d_in[0];
    const int*   ei    = (const int*)d_in[1];
    const int*   cpos  = (const int*)d_in[2];
    const int*   valid = (const int*)d_in[3];
    const int*   owned = (const int*)d_in[4];
    const float* Wl    = (const float*)d_in[5];
    const float* bl    = (const float*)d_in[6];
    const float* Wr    = (const float*)d_in[7];
    const float* br    = (const float*)d_in[8];
    const float* att   = (const float*)d_in[9];
    const float* gbias = (const float*)d_in[10];
    const float* Wm1 = (const float*)d_in[11];
    const float* bm1 = (const float*)d_in[12];
    const float* Wm2 = (const float*)d_in[13];
    const float* bm2 = (const float*)d_in[14];
    const float* Wp  = (const float*)d_in[15];
    const float* bp  = (const float*)d_in[16];
    const float* Wv1 = (const float*)d_in[17];
    const float* bv1 = (const float*)d_in[18];
    const float* Wv2 = (const float*)d_in[19];
    const float* bv2 = (const float*)d_in[20];
    float* out = (float*)d_out;

    int n = in_sizes[0] / 64;      // 50000
    int E = in_sizes[1] / 2;       // 800000
    const int* srcp = ei;
    const int* dstp = ei + E;

    // workspace carve
    char* w = (char*)d_ws;
    auto alloc = [&](size_t bytes) -> char* {
        char* p = w;
        w += (bytes + 255) & ~(size_t)255;
        return p;
    };
    __half* xlh     = (__half*)alloc((size_t)n * NHID * 2);
    __half* xrh     = (__half*)alloc((size_t)n * NHID * 2);
    float* hA       = (float*)alloc((size_t)n * 64 * 4);
    float* hB       = (float*)alloc((size_t)n * 64 * 4);
    __half* h16     = (__half*)alloc((size_t)n * 64 * 2);
    __half* Wfrag   = (__half*)alloc((size_t)LAYERS * 32768 * 2);
    float* gsum     = (float*)alloc(64 * 4);
    int*   row_ptr  = (int*)alloc((size_t)(n + 1) * 4);
    int*   row_fill = (int*)alloc((size_t)n * 4);
    int*   col_src  = (int*)alloc((size_t)(E + n + 16) * 4);
    int*   partials = (int*)alloc(256 * 4);

    int nblk = (n + 255) / 256;    // 196
    int nthr = E + n;              // edges + self loops

    // ---- CSR by dst (self loops included; col_src holds byte row offsets) ----
    hipMemsetAsync(row_fill, 0, (size_t)n * 4, stream);
    count_deg<<<(nthr + 255) / 256, 256, 0, stream>>>(dstp, row_fill, E, n);
    scan_partial<<<nblk, 256, 0, stream>>>(row_fill, row_ptr, partials, n);
    scan_partials_scan<<<1, 256, 0, stream>>>(partials, row_ptr, nblk, n);
    scan_add_offsets2<<<nblk, 256, 0, stream>>>(row_ptr, row_fill, partials, n);
    scatter_edges<<<(nthr + 255) / 256, 256, 0, stream>>>(srcp, dstp, row_fill, col_src, E, n);
    hipMemsetAsync(col_src + E + n, 0, 16 * 4, stream);  // pad for pair prefetch

    // ---- weight fragments + initial h16 ----
    wprep<<<LAYERS * 16, 256, 0, stream>>>(Wl, Wr, Wfrag);
    conv_h16<<<(n * 64 + 255) / 256, 256, 0, stream>>>(nf, h16, n * 64);

    // ---- 5 GATv2 layers ----
    const float* hin = nf;
    float* hnext = hB;
    for (int i = 0; i < LAYERS; ++i) {
        gemm_mfma<<<(n + 63) / 64, 256, 0, stream>>>(h16, Wfrag + (size_t)i * 32768,
                                                     bl + i * 256, br + i * 256,
                                                     xlh, xrh, n);
        const float* res = (i == 0) ? nullptr : hin;
        float* outp = (i == 0) ? hA : hnext;
        gat_node<<<(n + 3) / 4, 256, 0, stream>>>(xlh, xrh, row_ptr, col_src,
                                                  att + i * HEADS * 64, gbias + i * 64,
                                                  res, outp, h16, n);
        if (i == 0) {
            hin = hA; hnext = hB;
        } else {
            const float* t = hin;
            hin = outp;
            hnext = (float*)t;
        }
    }

    // ---- heads ----
    hipMemsetAsync(gsum, 0, 64 * 4, stream);
    col_sum<<<256, 256, 0, stream>>>(hin, gsum, n);
    heads_kernel<<<11, 128, 0, stream>>>(hin, gsum, cpos, valid, owned,
                                         Wm1, bm1, Wm2, bm2, Wp, bp,
                                         Wv1, bv1, Wv2, bv2, out, n);
}